// Round 4
// baseline (663.868 us; speedup 1.0000x reference)
//
#include <hip/hip_runtime.h>
#include <hip/hip_bf16.h>

#define T_TOK   16384
#define HID     4096
#define NEXP    64
#define NTOPK   8
#define CAPACITY 2048
#define TE      (T_TOK * NEXP)      // 1048576
#define NBLK2   (T_TOK / 64)        // 256 routing blocks
#define BT      256                 // tokens per gemm block-tile
#define BK      32                  // K-tile (floats)
#define KS      8                   // K-splits
#define NTILE   ((HID / KS) / BK)   // 16 tiles per block

// ---------------- K1: gate GEMM  lp[split][t][e] ------------------------------
// grid (T/256, 8) = 512 blocks (2/CU), block 256.
// 8 tok x 8 exp per thread (1.0 LDS-B/FMA), gload_lds w=16 staging, dbuf 80KB.
// ROUND-4 FIXES (round 3 spilled 178MB scratch at VGPR=128):
//  1. amdgpu_waves_per_eu(2,2): pins allocator budget to 512/2 = 256 VGPRs.
//     (min-only launch_bounds left the default 4-waves/EU target -> 128 cap.)
//     Costs nothing: 80KB LDS already caps residency at 2 blocks/CU = 2 wv/EU.
//  2. Per-chunk base pointers ab[8]/bb[8]: every ds_read = base + compile-time
//     immediate (i*BK). Kills 128 v_xor/tile of address math + their live temps.
//     Read addresses bit-identical to round 3 (absmax 0.0 verified).
__global__ __attribute__((amdgpu_waves_per_eu(2, 2))) __launch_bounds__(256)
void gemm_k(const float* __restrict__ x,
            const float* __restrict__ wg,
            float* __restrict__ lp) {
    __shared__ float xs[2][BT][BK];     // 64 KB
    __shared__ float wsh[2][NEXP][BK];  // 16 KB
    const int tid = threadIdx.x;
    const int tx = tid & 7, ty = tid >> 3;      // expert oct / token oct (0..31)
    const int t7 = ty & 7;
    const int t0 = blockIdx.x * BT;
    const int kbase = blockIdx.y * (HID / KS);  // klen = 512
    const int w = tid >> 6, lane = tid & 63;
    const int lr = lane >> 3, lc = lane & 7;

    auto stage = [&](int buf, int koff) {
        // x-tile: 32 issues of 1024B (8 per wave). dest linear: base + lane*16.
#pragma unroll
        for (int it = 0; it < 8; ++it) {
            const int br = w * 64 + it * 8;
            const int r = br + lr;
            const int cg = lc ^ ((r ^ (r >> 3)) & 7);
            const float* src = x + (size_t)(t0 + r) * HID + kbase + koff + cg * 4;
            __builtin_amdgcn_global_load_lds(
                (const __attribute__((address_space(1))) void*)src,
                (__attribute__((address_space(3))) void*)&xs[buf][br][0], 16, 0, 0);
        }
        // w-tile: 8 issues (2 per wave)
#pragma unroll
        for (int jt = 0; jt < 2; ++jt) {
            const int br = (w * 2 + jt) * 8;
            const int r = br + lr;
            const int cg = lc ^ ((r ^ (r >> 3)) & 7);
            const float* src = wg + (size_t)r * HID + kbase + koff + cg * 4;
            __builtin_amdgcn_global_load_lds(
                (const __attribute__((address_space(1))) void*)src,
                (__attribute__((address_space(3))) void*)&wsh[buf][br][0], 16, 0, 0);
        }
    };

    float acc[8][8];
#pragma unroll
    for (int i = 0; i < 8; ++i)
#pragma unroll
        for (int j = 0; j < 8; ++j) acc[i][j] = 0.f;

    stage(0, 0);
    int cur = 0;
    for (int tile = 0; tile < NTILE; ++tile) {
        __syncthreads();                 // vmcnt(0) drain: buf[cur] ready,
                                         // all waves done with buf[cur^1]
        if (tile + 1 < NTILE) stage(cur ^ 1, (tile + 1) * BK);
        // per-chunk base pointers: chunk c = kc^i (A) / kc^j (B)
        const float* ab[8];
        const float* bb[8];
#pragma unroll
        for (int c = 0; c < 8; ++c) {
            ab[c] = &xs[cur][ty * 8][(c ^ t7) << 2];
            bb[c] = &wsh[cur][tx * 8][(c ^ tx) << 2];
        }
#pragma unroll
        for (int kc = 0; kc < 8; ++kc) {
            float4 a[8];
#pragma unroll
            for (int i = 0; i < 8; ++i)
                a[i] = *(const float4*)(ab[kc ^ i] + i * BK);   // base + imm
#pragma unroll
            for (int j = 0; j < 8; ++j) {
                float4 b = *(const float4*)(bb[kc ^ j] + j * BK);
#pragma unroll
                for (int i = 0; i < 8; ++i) {
                    acc[i][j] = fmaf(a[i].x, b.x, acc[i][j]);
                    acc[i][j] = fmaf(a[i].y, b.y, acc[i][j]);
                    acc[i][j] = fmaf(a[i].z, b.z, acc[i][j]);
                    acc[i][j] = fmaf(a[i].w, b.w, acc[i][j]);
                }
            }
        }
        cur ^= 1;
    }
    float* op = lp + (size_t)blockIdx.y * TE + (size_t)(t0 + ty * 8) * NEXP + tx * 8;
#pragma unroll
    for (int i = 0; i < 8; ++i) {
        *(float4*)(op + (size_t)i * NEXP) =
            make_float4(acc[i][0], acc[i][1], acc[i][2], acc[i][3]);
        *(float4*)(op + (size_t)i * NEXP + 4) =
            make_float4(acc[i][4], acc[i][5], acc[i][6], acc[i][7]);
    }
}

// ---------------- K2: softmax + group-limited top-k routing -------------------
// grid T/64, block 1024 (16 waves x 4 tokens each). lane = expert.
__global__ __launch_bounds__(1024) void route_k(const float* __restrict__ lp,
                                                int* __restrict__ ws_idx,
                                                float* __restrict__ ws_prob,
                                                int* __restrict__ ws_rank,
                                                int* __restrict__ ws_hist,
                                                float* __restrict__ ws_gsum) {
    __shared__ unsigned char idx_lds[64][8];
    __shared__ float gsum_lds[16][64];
    const int tid = threadIdx.x, lane = tid & 63, w = tid >> 6;
    const int blk = blockIdx.x;

    float gacc = 0.f;
    for (int i = 0; i < 4; ++i) {
        const int tloc = w * 4 + i;
        const int t = blk * 64 + tloc;
        float lg = 0.f;
        for (int s = 0; s < KS; ++s)
            lg += lp[(size_t)s * TE + (size_t)t * NEXP + lane];
        // softmax over 64 experts
        float m = lg;
#pragma unroll
        for (int off = 32; off; off >>= 1) m = fmaxf(m, __shfl_xor(m, off));
        float p = expf(lg - m);
        float s = p;
#pragma unroll
        for (int off = 32; off; off >>= 1) s += __shfl_xor(s, off);
        float gate = p / s;
        // group scores (max over 8 lanes within group), then top-4 groups
        float gsc = gate;
#pragma unroll
        for (int off = 1; off < 8; off <<= 1) gsc = fmaxf(gsc, __shfl_xor(gsc, off));
        const int g = lane >> 3;
        int grank = 0;
#pragma unroll
        for (int gg = 0; gg < 8; ++gg) {
            float o = __shfl(gsc, gg * 8);
            grank += (o > gsc || (o == gsc && gg < g)) ? 1 : 0;
        }
        float gm = (grank < 4) ? gate : 0.f;
        gacc += gm;
        // top-8 over 64 lanes; ties toward lower lane (lax.top_k)
        unsigned long long key =
            ((unsigned long long)__float_as_uint(gm) << 32) | (unsigned long long)(63 - lane);
        float dsum = 0.f;
        int my_e = 0; float my_v = 0.f;
#pragma unroll
        for (int r = 0; r < NTOPK; ++r) {
            unsigned long long b = key;
#pragma unroll
            for (int off = 32; off; off >>= 1) {
                unsigned long long o = __shfl_xor(b, off);
                b = (o > b) ? o : b;
            }
            int be = 63 - (int)(b & 63ull);
            float bv = __uint_as_float((unsigned)(b >> 32));
            dsum += bv;
            if (lane == r) { my_e = be; my_v = bv; }
            if (lane == be) key = 0ull;
        }
        float denom = fmaxf(dsum, 1.1920929e-7f);
        if (lane < NTOPK) {
            ws_idx[(size_t)t * NTOPK + lane]  = my_e;
            ws_prob[(size_t)t * NTOPK + lane] = my_v / denom;
            idx_lds[tloc][lane] = (unsigned char)my_e;
        }
    }
    gsum_lds[w][lane] = gacc;
    __syncthreads();
    // rank + hist via ballot: wave w<8 handles slot w; lane = token
    if (w < NTOPK) {
        const unsigned long long ltmask = (1ull << lane) - 1ull;
        const int ev = idx_lds[lane][w];
        int rank = 0, hc = 0;
        for (int e0 = 0; e0 < NEXP; ++e0) {
            unsigned long long msk = __ballot(ev == e0);
            if (ev == e0) rank = __popcll(msk & ltmask);
            if (lane == e0) hc = __popcll(msk);
        }
        ws_rank[(size_t)(blk * 64 + lane) * NTOPK + w] = rank;
        ws_hist[(size_t)(w * NEXP + lane) * NBLK2 + blk] = hc;  // [bin][block]
    }
    if (tid < 64) {
        float sg = 0.f;
#pragma unroll
        for (int ww = 0; ww < 16; ++ww) sg += gsum_lds[ww][tid];
        ws_gsum[(size_t)blk * NEXP + tid] = sg;
    }
}

// ---------------- K3a: per-bin exclusive scan, 1 wave per bin -----------------
__global__ __launch_bounds__(512) void scan_k(const int* __restrict__ hist,
                                              int* __restrict__ offs,
                                              int* __restrict__ tot) {
    const int bin = blockIdx.x * 8 + (threadIdx.x >> 6);
    const int lane = threadIdx.x & 63;
    int4 v = ((const int4*)(hist + (size_t)bin * NBLK2))[lane];
    int s = v.x + v.y + v.z + v.w;
    int incl = s;
#pragma unroll
    for (int off = 1; off < 64; off <<= 1) {
        int n = __shfl_up(incl, off);
        if (lane >= off) incl += n;
    }
    int excl = incl - s;
    int4 o;
    o.x = excl; o.y = excl + v.x; o.z = o.y + v.y; o.w = o.z + v.z;
    ((int4*)(offs + (size_t)bin * NBLK2))[lane] = o;
    if (lane == 63) tot[bin] = incl;
}

// ---------------- K3b: slot bases + scalar outputs ----------------------------
__global__ __launch_bounds__(256) void finalize_k(const int* __restrict__ tot,
                                                  const float* __restrict__ gsum,
                                                  int* __restrict__ base,
                                                  float* __restrict__ out) {
    __shared__ int tl[512];
    __shared__ float gl[256];
    const int tid = threadIdx.x;
    for (int i = tid; i < 512; i += 256) tl[i] = tot[i];
    {
        const int e = tid & 63, q = tid >> 6;
        float p = 0.f;
        for (int b = q * 64; b < q * 64 + 64; ++b) p += gsum[(size_t)b * NEXP + e];
        gl[tid] = p;
    }
    __syncthreads();
    for (int i = tid; i < 512; i += 256) {
        const int k = i >> 6, e = i & 63;
        int b = 0;
        for (int kk = 0; kk < k; ++kk) b += tl[kk * NEXP + e];
        base[i] = b;
    }
    if (tid < 64) {
        int cnt = 0;
#pragma unroll
        for (int k = 0; k < NTOPK; ++k) cnt += tl[k * NEXP + tid];
        out[2 + 3 * TE + tid] = (float)cnt;          // exp_counts
        float sg = gl[tid] + gl[64 + tid] + gl[128 + tid] + gl[192 + tid];
        float lx = (float)cnt * sg;
        int vs = cnt < CAPACITY ? cnt : CAPACITY;
#pragma unroll
        for (int off = 32; off; off >>= 1) {
            lx += __shfl_xor(lx, off);
            vs += __shfl_xor(vs, off);
        }
        if (tid == 0) {
            out[0] = 64.0f * lx / 268435456.0f;      // E^2 * sum / T^2
            out[1] = (float)vs / 131072.0f;          // / (T*TOPK)
        }
    }
}

// ---------------- K4: dense [T,64] combine / priority / valid -----------------
__global__ __launch_bounds__(256) void output_k(const int* __restrict__ ws_idx,
                                                const float* __restrict__ ws_prob,
                                                const int* __restrict__ ws_rank,
                                                const int* __restrict__ offs,
                                                const int* __restrict__ base,
                                                float* __restrict__ out) {
    const int gid = blockIdx.x * 256 + threadIdx.x;   // 0..TE/4-1
    const int t = gid >> 4, e0 = (gid & 15) << 2;
    const int4* ip = (const int4*)(ws_idx + (size_t)t * NTOPK);
    int4 ia = ip[0], ib = ip[1];
    int i8[NTOPK] = {ia.x, ia.y, ia.z, ia.w, ib.x, ib.y, ib.z, ib.w};
    float cw[4] = {0.f, 0.f, 0.f, 0.f}, pr[4] = {0.f, 0.f, 0.f, 0.f},
          vm[4] = {0.f, 0.f, 0.f, 0.f};
#pragma unroll
    for (int j = 0; j < 4; ++j) {
        const int e = e0 + j;
        int found = -1;
#pragma unroll
        for (int k = 0; k < NTOPK; ++k) if (i8[k] == e) found = k;
        if (found >= 0) {
            const int bin = found * NEXP + e;
            int pos = base[bin] + offs[(size_t)bin * NBLK2 + (t >> 6)] +
                      ws_rank[(size_t)t * NTOPK + found];
            if (pos < CAPACITY) {
                cw[j] = ws_prob[(size_t)t * NTOPK + found];
                pr[j] = (float)pos;
                vm[j] = 1.f;
            }
        }
    }
    ((float4*)(out + 2))[gid]          = make_float4(cw[0], cw[1], cw[2], cw[3]);
    ((float4*)(out + 2 + TE))[gid]     = make_float4(pr[0], pr[1], pr[2], pr[3]);
    ((float4*)(out + 2 + 2 * TE))[gid] = make_float4(vm[0], vm[1], vm[2], vm[3]);
}

// ---------------- launch ------------------------------------------------------
extern "C" void kernel_launch(void* const* d_in, const int* in_sizes, int n_in,
                              void* d_out, int out_size, void* d_ws, size_t ws_size,
                              hipStream_t stream) {
    const float* x  = (const float*)d_in[0];   // [16384, 4096] fp32
    const float* wg = (const float*)d_in[1];   // [64, 4096] fp32
    float* out = (float*)d_out;
    char* ws = (char*)d_ws;

    const size_t lp_bytes = (size_t)KS * TE * 4;   // 32 MB

    float* lp   = (float*)(ws);
    char*  rest = ws + lp_bytes;
    int*   idxw = (int*)  (rest);               // 512 KB
    float* prob = (float*)(rest + 524288);      // 512 KB
    int*   rank = (int*)  (rest + 1048576);     // 512 KB
    int*   hist = (int*)  (rest + 1572864);     // 512 KB  [bin][block]
    int*   offs = (int*)  (rest + 2097152);     // 512 KB  [bin][block]
    float* gsum = (float*)(rest + 2621440);     // 64 KB
    int*   tot  = (int*)  (rest + 2686976);     // 2 KB
    int*   base = (int*)  (rest + 2691072);     // 2 KB

    dim3 g1(T_TOK / BT, KS);
    gemm_k<<<g1, 256, 0, stream>>>(x, wg, lp);
    route_k<<<NBLK2, 1024, 0, stream>>>(lp, idxw, prob, rank, hist, gsum);
    scan_k<<<64, 512, 0, stream>>>(hist, offs, tot);
    finalize_k<<<1, 256, 0, stream>>>(tot, gsum, base, out);
    output_k<<<TE / 4 / 256, 256, 0, stream>>>(idxw, prob, rank, offs, base, out);
}

// Round 5
// 517.420 us; speedup vs baseline: 1.2830x; 1.2830x over previous
//
#include <hip/hip_runtime.h>
#include <hip/hip_bf16.h>

#define T_TOK   16384
#define HID     4096
#define NEXP    64
#define NTOPK   8
#define CAPACITY 2048
#define TE      (T_TOK * NEXP)      // 1048576
#define NBLK2   (T_TOK / 64)        // 256 routing blocks
#define BT      128                 // tokens per gemm block-tile
#define BK      32                  // K-tile (floats)
#define KS      8                   // K-splits
#define NTILE   ((HID / KS) / BK)   // 16 tiles per block

// ---------------- K1: gate GEMM  lp[split][t][e] ------------------------------
// grid (T/128, 8) = 1024 blocks, block 256, 48 KB LDS -> 3 blocks/CU resident.
// ROUND-5: revert to the 8 tok x 4 exp shape (proven spill-free in round 1;
// rounds 2-4 proved the allocator pins VGPR=128 and the 8x8 tile's ~150-reg
// demand spills ~180-330 MB of scratch). Keep the two verified upgrades:
//  - global_load_lds w=16 staging (zero staging VGPRs / ds_writes); XOR
//    swizzle on the GLOBAL source chunk, mirrored on the read. Verified
//    absmax 0.0 + SQ_LDS_BANK_CONFLICT=0 in rounds 3-4.
//  - compile-time double-buffer (tile-pair unroll) -> static LDS bases.
// VGPR demand: acc 32 + a[8] 32 + b 4 + addr ~ 90 << 128. No allocator fight.
__global__ __launch_bounds__(256) void gemm_k(const float* __restrict__ x,
                                              const float* __restrict__ wg,
                                              float* __restrict__ lp) {
    __shared__ float xs[2][BT][BK];     // 32 KB
    __shared__ float wsh[2][NEXP][BK];  // 16 KB
    const int tid = threadIdx.x;
    const int tx = tid & 15, ty = tid >> 4;     // expert quad / token oct (0..15)
    const int t7 = ty & 7;
    const int t0 = blockIdx.x * BT;
    const int kbase = blockIdx.y * (HID / KS);  // klen = 512
    const int w = tid >> 6, lane = tid & 63;
    const int lr = lane >> 3, lc = lane & 7;

    auto stage = [&](int buf, int koff) {
        // x-tile: 16 issues of 1024B (4 per wave); dest linear base + lane*16
#pragma unroll
        for (int it = 0; it < 4; ++it) {
            const int br = w * 32 + it * 8;
            const int r = br + lr;
            const int cg = lc ^ ((r ^ (r >> 3)) & 7);
            const float* src = x + (size_t)(t0 + r) * HID + kbase + koff + cg * 4;
            __builtin_amdgcn_global_load_lds(
                (const __attribute__((address_space(1))) void*)src,
                (__attribute__((address_space(3))) void*)&xs[buf][br][0], 16, 0, 0);
        }
        // w-tile: 8 issues (2 per wave)
#pragma unroll
        for (int jt = 0; jt < 2; ++jt) {
            const int br = (w * 2 + jt) * 8;
            const int r = br + lr;
            const int cg = lc ^ ((r ^ (r >> 3)) & 7);
            const float* src = wg + (size_t)r * HID + kbase + koff + cg * 4;
            __builtin_amdgcn_global_load_lds(
                (const __attribute__((address_space(1))) void*)src,
                (__attribute__((address_space(3))) void*)&wsh[buf][br][0], 16, 0, 0);
        }
    };

    float acc[8][4];
#pragma unroll
    for (int i = 0; i < 8; ++i)
#pragma unroll
        for (int j = 0; j < 4; ++j) acc[i][j] = 0.f;

    auto compute = [&](int buf) {   // buf is a literal at every call site
#pragma unroll
        for (int kc = 0; kc < 8; ++kc) {
            float4 a[8];
#pragma unroll
            for (int i = 0; i < 8; ++i)
                a[i] = *(const float4*)&xs[buf][ty * 8 + i][((kc ^ i ^ t7) & 7) << 2];
#pragma unroll
            for (int j = 0; j < 4; ++j) {
                const int rB = tx * 4 + j;
                const int cB = (kc ^ ((rB ^ (rB >> 3)) & 7)) & 7;
                float4 b = *(const float4*)&wsh[buf][rB][cB << 2];
#pragma unroll
                for (int i = 0; i < 8; ++i) {
                    acc[i][j] = fmaf(a[i].x, b.x, acc[i][j]);
                    acc[i][j] = fmaf(a[i].y, b.y, acc[i][j]);
                    acc[i][j] = fmaf(a[i].z, b.z, acc[i][j]);
                    acc[i][j] = fmaf(a[i].w, b.w, acc[i][j]);
                }
            }
        }
    };

    stage(0, 0);
#pragma unroll 1
    for (int tp = 0; tp < NTILE; tp += 2) {
        __syncthreads();                        // drains stage into buf 0
        if (tp + 1 < NTILE) stage(1, (tp + 1) * BK);
        compute(0);
        __syncthreads();                        // drains stage into buf 1
        if (tp + 2 < NTILE) stage(0, (tp + 2) * BK);
        compute(1);
    }
    float* op = lp + (size_t)blockIdx.y * TE + (size_t)(t0 + ty * 8) * NEXP + tx * 4;
#pragma unroll
    for (int i = 0; i < 8; ++i)
        *(float4*)(op + (size_t)i * NEXP) =
            make_float4(acc[i][0], acc[i][1], acc[i][2], acc[i][3]);
}

// ---------------- K2: softmax + group-limited top-k routing -------------------
// grid T/64, block 1024 (16 waves x 4 tokens each). lane = expert.
__global__ __launch_bounds__(1024) void route_k(const float* __restrict__ lp,
                                                int* __restrict__ ws_idx,
                                                float* __restrict__ ws_prob,
                                                int* __restrict__ ws_rank,
                                                int* __restrict__ ws_hist,
                                                float* __restrict__ ws_gsum) {
    __shared__ unsigned char idx_lds[64][8];
    __shared__ float gsum_lds[16][64];
    const int tid = threadIdx.x, lane = tid & 63, w = tid >> 6;
    const int blk = blockIdx.x;

    float gacc = 0.f;
    for (int i = 0; i < 4; ++i) {
        const int tloc = w * 4 + i;
        const int t = blk * 64 + tloc;
        float lg = 0.f;
        for (int s = 0; s < KS; ++s)
            lg += lp[(size_t)s * TE + (size_t)t * NEXP + lane];
        // softmax over 64 experts
        float m = lg;
#pragma unroll
        for (int off = 32; off; off >>= 1) m = fmaxf(m, __shfl_xor(m, off));
        float p = expf(lg - m);
        float s = p;
#pragma unroll
        for (int off = 32; off; off >>= 1) s += __shfl_xor(s, off);
        float gate = p / s;
        // group scores (max over 8 lanes within group), then top-4 groups
        float gsc = gate;
#pragma unroll
        for (int off = 1; off < 8; off <<= 1) gsc = fmaxf(gsc, __shfl_xor(gsc, off));
        const int g = lane >> 3;
        int grank = 0;
#pragma unroll
        for (int gg = 0; gg < 8; ++gg) {
            float o = __shfl(gsc, gg * 8);
            grank += (o > gsc || (o == gsc && gg < g)) ? 1 : 0;
        }
        float gm = (grank < 4) ? gate : 0.f;
        gacc += gm;
        // top-8 over 64 lanes; ties toward lower lane (lax.top_k)
        unsigned long long key =
            ((unsigned long long)__float_as_uint(gm) << 32) | (unsigned long long)(63 - lane);
        float dsum = 0.f;
        int my_e = 0; float my_v = 0.f;
#pragma unroll
        for (int r = 0; r < NTOPK; ++r) {
            unsigned long long b = key;
#pragma unroll
            for (int off = 32; off; off >>= 1) {
                unsigned long long o = __shfl_xor(b, off);
                b = (o > b) ? o : b;
            }
            int be = 63 - (int)(b & 63ull);
            float bv = __uint_as_float((unsigned)(b >> 32));
            dsum += bv;
            if (lane == r) { my_e = be; my_v = bv; }
            if (lane == be) key = 0ull;
        }
        float denom = fmaxf(dsum, 1.1920929e-7f);
        if (lane < NTOPK) {
            ws_idx[(size_t)t * NTOPK + lane]  = my_e;
            ws_prob[(size_t)t * NTOPK + lane] = my_v / denom;
            idx_lds[tloc][lane] = (unsigned char)my_e;
        }
    }
    gsum_lds[w][lane] = gacc;
    __syncthreads();
    // rank + hist via ballot: wave w<8 handles slot w; lane = token
    if (w < NTOPK) {
        const unsigned long long ltmask = (1ull << lane) - 1ull;
        const int ev = idx_lds[lane][w];
        int rank = 0, hc = 0;
        for (int e0 = 0; e0 < NEXP; ++e0) {
            unsigned long long msk = __ballot(ev == e0);
            if (ev == e0) rank = __popcll(msk & ltmask);
            if (lane == e0) hc = __popcll(msk);
        }
        ws_rank[(size_t)(blk * 64 + lane) * NTOPK + w] = rank;
        ws_hist[(size_t)(w * NEXP + lane) * NBLK2 + blk] = hc;  // [bin][block]
    }
    if (tid < 64) {
        float sg = 0.f;
#pragma unroll
        for (int ww = 0; ww < 16; ++ww) sg += gsum_lds[ww][tid];
        ws_gsum[(size_t)blk * NEXP + tid] = sg;
    }
}

// ---------------- K3a: per-bin exclusive scan, 1 wave per bin -----------------
__global__ __launch_bounds__(512) void scan_k(const int* __restrict__ hist,
                                              int* __restrict__ offs,
                                              int* __restrict__ tot) {
    const int bin = blockIdx.x * 8 + (threadIdx.x >> 6);
    const int lane = threadIdx.x & 63;
    int4 v = ((const int4*)(hist + (size_t)bin * NBLK2))[lane];
    int s = v.x + v.y + v.z + v.w;
    int incl = s;
#pragma unroll
    for (int off = 1; off < 64; off <<= 1) {
        int n = __shfl_up(incl, off);
        if (lane >= off) incl += n;
    }
    int excl = incl - s;
    int4 o;
    o.x = excl; o.y = excl + v.x; o.z = o.y + v.y; o.w = o.z + v.z;
    ((int4*)(offs + (size_t)bin * NBLK2))[lane] = o;
    if (lane == 63) tot[bin] = incl;
}

// ---------------- K3b: slot bases + scalar outputs ----------------------------
__global__ __launch_bounds__(256) void finalize_k(const int* __restrict__ tot,
                                                  const float* __restrict__ gsum,
                                                  int* __restrict__ base,
                                                  float* __restrict__ out) {
    __shared__ int tl[512];
    __shared__ float gl[256];
    const int tid = threadIdx.x;
    for (int i = tid; i < 512; i += 256) tl[i] = tot[i];
    {
        const int e = tid & 63, q = tid >> 6;
        float p = 0.f;
        for (int b = q * 64; b < q * 64 + 64; ++b) p += gsum[(size_t)b * NEXP + e];
        gl[tid] = p;
    }
    __syncthreads();
    for (int i = tid; i < 512; i += 256) {
        const int k = i >> 6, e = i & 63;
        int b = 0;
        for (int kk = 0; kk < k; ++kk) b += tl[kk * NEXP + e];
        base[i] = b;
    }
    if (tid < 64) {
        int cnt = 0;
#pragma unroll
        for (int k = 0; k < NTOPK; ++k) cnt += tl[k * NEXP + tid];
        out[2 + 3 * TE + tid] = (float)cnt;          // exp_counts
        float sg = gl[tid] + gl[64 + tid] + gl[128 + tid] + gl[192 + tid];
        float lx = (float)cnt * sg;
        int vs = cnt < CAPACITY ? cnt : CAPACITY;
#pragma unroll
        for (int off = 32; off; off >>= 1) {
            lx += __shfl_xor(lx, off);
            vs += __shfl_xor(vs, off);
        }
        if (tid == 0) {
            out[0] = 64.0f * lx / 268435456.0f;      // E^2 * sum / T^2
            out[1] = (float)vs / 131072.0f;          // / (T*TOPK)
        }
    }
}

// ---------------- K4: dense [T,64] combine / priority / valid -----------------
__global__ __launch_bounds__(256) void output_k(const int* __restrict__ ws_idx,
                                                const float* __restrict__ ws_prob,
                                                const int* __restrict__ ws_rank,
                                                const int* __restrict__ offs,
                                                const int* __restrict__ base,
                                                float* __restrict__ out) {
    const int gid = blockIdx.x * 256 + threadIdx.x;   // 0..TE/4-1
    const int t = gid >> 4, e0 = (gid & 15) << 2;
    const int4* ip = (const int4*)(ws_idx + (size_t)t * NTOPK);
    int4 ia = ip[0], ib = ip[1];
    int i8[NTOPK] = {ia.x, ia.y, ia.z, ia.w, ib.x, ib.y, ib.z, ib.w};
    float cw[4] = {0.f, 0.f, 0.f, 0.f}, pr[4] = {0.f, 0.f, 0.f, 0.f},
          vm[4] = {0.f, 0.f, 0.f, 0.f};
#pragma unroll
    for (int j = 0; j < 4; ++j) {
        const int e = e0 + j;
        int found = -1;
#pragma unroll
        for (int k = 0; k < NTOPK; ++k) if (i8[k] == e) found = k;
        if (found >= 0) {
            const int bin = found * NEXP + e;
            int pos = base[bin] + offs[(size_t)bin * NBLK2 + (t >> 6)] +
                      ws_rank[(size_t)t * NTOPK + found];
            if (pos < CAPACITY) {
                cw[j] = ws_prob[(size_t)t * NTOPK + found];
                pr[j] = (float)pos;
                vm[j] = 1.f;
            }
        }
    }
    ((float4*)(out + 2))[gid]          = make_float4(cw[0], cw[1], cw[2], cw[3]);
    ((float4*)(out + 2 + TE))[gid]     = make_float4(pr[0], pr[1], pr[2], pr[3]);
    ((float4*)(out + 2 + 2 * TE))[gid] = make_float4(vm[0], vm[1], vm[2], vm[3]);
}

// ---------------- launch ------------------------------------------------------
extern "C" void kernel_launch(void* const* d_in, const int* in_sizes, int n_in,
                              void* d_out, int out_size, void* d_ws, size_t ws_size,
                              hipStream_t stream) {
    const float* x  = (const float*)d_in[0];   // [16384, 4096] fp32
    const float* wg = (const float*)d_in[1];   // [64, 4096] fp32
    float* out = (float*)d_out;
    char* ws = (char*)d_ws;

    const size_t lp_bytes = (size_t)KS * TE * 4;   // 32 MB

    float* lp   = (float*)(ws);
    char*  rest = ws + lp_bytes;
    int*   idxw = (int*)  (rest);               // 512 KB
    float* prob = (float*)(rest + 524288);      // 512 KB
    int*   rank = (int*)  (rest + 1048576);     // 512 KB
    int*   hist = (int*)  (rest + 1572864);     // 512 KB  [bin][block]
    int*   offs = (int*)  (rest + 2097152);     // 512 KB  [bin][block]
    float* gsum = (float*)(rest + 2621440);     // 64 KB
    int*   tot  = (int*)  (rest + 2686976);     // 2 KB
    int*   base = (int*)  (rest + 2691072);     // 2 KB

    dim3 g1(T_TOK / BT, KS);
    gemm_k<<<g1, 256, 0, stream>>>(x, wg, lp);
    route_k<<<NBLK2, 1024, 0, stream>>>(lp, idxw, prob, rank, hist, gsum);
    scan_k<<<64, 512, 0, stream>>>(hist, offs, tot);
    finalize_k<<<1, 256, 0, stream>>>(tot, gsum, base, out);
    output_k<<<TE / 4 / 256, 256, 0, stream>>>(idxw, prob, rank, offs, base, out);
}